// Round 19
// baseline (172.616 us; speedup 1.0000x reference)
//
#include <hip/hip_runtime.h>

#define N_NODES 40000
#define N_EDGES 160000
#define N_FEATS 74
#define DD 1024
#define HD 3072
#define N_GRAPHS 800

#define MAGIC 0x5F3759DFu
// block roles (all 512 threads, 8 waves)
#define NVB   96            // v-blocks: 32 g's each
#define NLRB  28            // L/R task blocks: 8 wave-tasks each (222 + c0)
#define NNB   157           // node blocks: 256 nodes each
#define NSB   200           // scan blocks: 200 dsts = 4 graphs each
#define B_LR0 (NVB)                 // 96
#define B_N0  (NVB + NLRB)          // 124
#define B_S0  (NVB + NLRB + NNB)    // 281
#define NBLK  (B_S0 + NSB)          // 481
#define NFLAGA (NVB + NLRB)         // 124
#define NFLAGB (NNB)                // 157
#define SRNG 200

__device__ __forceinline__ float waveReduceSum(float v) {
    #pragma unroll
    for (int off = 32; off > 0; off >>= 1)
        v += __shfl_down(v, off, 64);
    return v;
}
__device__ __forceinline__ float lrelu02(float x) { return x > 0.f ? x : 0.2f * x; }

__device__ __forceinline__ void signalFlag(unsigned* slot) {
    __threadfence();                 // each thread's writes globally visible
    __syncthreads();                 // all threads' fences complete
    if (threadIdx.x == 0)
        __hip_atomic_store(slot, MAGIC, __ATOMIC_RELEASE, __HIP_MEMORY_SCOPE_AGENT);
}

// all threads spin until flags[0..n) == MAGIC (tid i checks slot i)
__device__ __forceinline__ void waitFlagsA(const unsigned* fA, int nA,
                                           const unsigned* fB, int nB) {
    int tid = threadIdx.x;
    for (;;) {
        bool ok = true;
        if (tid < nA)
            ok = (__hip_atomic_load(&fA[tid], __ATOMIC_RELAXED,
                                    __HIP_MEMORY_SCOPE_AGENT) == MAGIC);
        else if (tid < nA + nB)
            ok = (__hip_atomic_load(&fB[tid - nA], __ATOMIC_RELAXED,
                                    __HIP_MEMORY_SCOPE_AGENT) == MAGIC);
        if (__syncthreads_and(ok)) break;
        __builtin_amdgcn_s_sleep(16);
    }
    __threadfence();                 // acquire
}

__device__ __forceinline__ void processBatch(const int* myq, int wtail, int lane, int nact,
        const int* __restrict__ src, const float4* __restrict__ sn4,
        const float4* __restrict__ er4, int rbase, float* acc) {
    if (lane < nact) {
        int pk = myq[(wtail + lane) & 127];
        int rr = pk & 255;
        int e  = ((unsigned)pk) >> 8;
        int s  = src[e];
        float4 L = sn4[s * 2];
        float4 V = sn4[s * 2 + 1];
        float4 R = er4[rbase + rr];
        float e0 = expf(lrelu02(L.x + R.x));
        float e1 = expf(lrelu02(L.y + R.y));
        float e2 = expf(lrelu02(L.z + R.z));
        float* p = acc + rr * 6;
        atomicAdd(p + 0, e0 * V.x);
        atomicAdd(p + 1, e1 * V.y);
        atomicAdd(p + 2, e2 * V.z);
        atomicAdd(p + 3, e0);
        atomicAdd(p + 4, e1);
        atomicAdd(p + 5, e2);
    }
}

__global__ __launch_bounds__(512, 8) void kMega(
    const float* __restrict__ feats, const float* __restrict__ W,
    const float* __restrict__ al, const float* __restrict__ ar,
    const float* __restrict__ bias, const float* __restrict__ W1,
    const float* __restrict__ b1, const float* __restrict__ W2,
    const float* __restrict__ b2, const int* __restrict__ src,
    const int* __restrict__ dst, float* __restrict__ ws,
    float* __restrict__ y) {
    // workspace layout
    unsigned* flagA = (unsigned*)ws;             // 124 (pad to 128)
    unsigned* flagB = (unsigned*)ws + 128;       // 157 (pad)
    float* lw6    = ws + 512;                    // 444
    float* c0     = ws + 960;                    // 1
    float* bgvpar = ws + 1024;                   // 96
    float* wvpar  = ws + 1536;                   // 96*80
    float* sn     = ws + 16384;                  // N*8 (16B aligned)
    float* er     = sn + N_NODES * 8;            // N*4

    const int b = blockIdx.x;
    const int tid = threadIdx.x;
    const int wave = tid >> 6, lane = tid & 63;

    if (b < NVB) {
        // ---- v-block: 32 g's; wvpar[b*80+f] = sum_j W[f,g0+j]*v[g0+j] ----
        __shared__ float vs[32];
        int g0 = b * 32;
        const float4* w2v = (const float4*)W2;
        #pragma unroll
        for (int q = 0; q < 4; ++q) {
            int g = g0 + wave * 4 + q;
            const float4* row = (const float4*)(W1 + (size_t)g * DD);
            float acc = 0.f;
            #pragma unroll
            for (int k = 0; k < 4; ++k) {
                float4 a = row[lane + 64 * k];
                float4 bb = w2v[lane + 64 * k];
                acc += a.x * bb.x + a.y * bb.y + a.z * bb.z + a.w * bb.w;
            }
            acc = waveReduceSum(acc);
            if (!lane) vs[wave * 4 + q] = acc;
        }
        __syncthreads();
        if (tid < N_FEATS) {
            const float4* wr = (const float4*)(W + (size_t)tid * HD + g0);
            const float4* vv = (const float4*)vs;
            float s = 0.f;
            #pragma unroll
            for (int k = 0; k < 8; ++k) {
                float4 a = wr[k];
                float4 bb = vv[k];
                s += a.x * bb.x + a.y * bb.y + a.z * bb.z + a.w * bb.w;
            }
            wvpar[b * 80 + tid] = s;
        } else if (tid == N_FEATS) {
            float s = 0.f;
            #pragma unroll
            for (int j = 0; j < 32; ++j) s += vs[j] * bias[g0 + j];
            bgvpar[b] = s;
        }
        signalFlag(&flagA[b]);
    } else if (b < B_N0) {
        // ---- L/R task block: t<222 -> lw6; t==222 -> c0 ----
        int t = (b - B_LR0) * 8 + wave;
        if (t < N_FEATS * 3) {
            int f = t / 3, h = t - f * 3;
            const float4* rw = (const float4*)(W + (size_t)f * HD + h * DD);
            const float4* pl = (const float4*)(al + h * DD);
            const float4* pr = (const float4*)(ar + h * DD);
            float aL = 0.f, aR = 0.f;
            #pragma unroll
            for (int k = 0; k < 4; ++k) {
                float4 x = rw[lane + 64 * k];
                float4 l4 = pl[lane + 64 * k];
                float4 r4 = pr[lane + 64 * k];
                aL += x.x * l4.x + x.y * l4.y + x.z * l4.z + x.w * l4.w;
                aR += x.x * r4.x + x.y * r4.y + x.z * r4.z + x.w * r4.w;
            }
            aL = waveReduceSum(aL); aR = waveReduceSum(aR);
            if (!lane) { lw6[f * 6 + h] = aL; lw6[f * 6 + 3 + h] = aR; }
        } else if (t == N_FEATS * 3) {
            const float4* pb1 = (const float4*)b1;
            const float4* w2v = (const float4*)W2;
            float acc = 0.f;
            #pragma unroll
            for (int k = 0; k < 4; ++k) {
                float4 a = pb1[lane + 64 * k];
                float4 bb = w2v[lane + 64 * k];
                acc += a.x * bb.x + a.y * bb.y + a.z * bb.z + a.w * bb.w;
            }
            acc = waveReduceSum(acc);
            if (!lane) c0[0] = acc + b2[0];
        }
        signalFlag(&flagA[b]);
    } else if (b < B_S0) {
        // ---- node block: 256 nodes, 2 threads/node ----
        __shared__ float lw[N_FEATS * 9];
        waitFlagsA(flagA, NFLAGA, flagA, 0);
        for (int i = tid; i < N_FEATS * 6; i += 512)
            lw[(i / 6) * 9 + (i % 6)] = lw6[i];
        for (int j = tid; j < N_FEATS * 3; j += 512) {   // j = f*3+h
            int f = j / 3, h = j - f * 3;
            float s = 0.f;
            #pragma unroll 8
            for (int bb = 0; bb < 32; ++bb)
                s += wvpar[(h * 32 + bb) * 80 + f];
            lw[f * 9 + 6 + h] = s;
        }
        __syncthreads();
        int node = (b - B_N0) * 256 + (tid >> 1);
        if (node < N_NODES) {
            int half = tid & 1;
            const float* row = feats + (size_t)node * N_FEATS;
            float a0=0,a1=0,a2=0,a3=0,a4=0,a5=0,a6=0,a7=0,a8=0;
            if (half == 0) {
                #pragma unroll
                for (int k = 0; k < 18; ++k) {
                    float2 x2 = *(const float2*)(row + k * 2);
                    const float* w0 = lw + (k * 2) * 9;
                    a0 += x2.x*w0[0]; a1 += x2.x*w0[1]; a2 += x2.x*w0[2];
                    a3 += x2.x*w0[3]; a4 += x2.x*w0[4]; a5 += x2.x*w0[5];
                    a6 += x2.x*w0[6]; a7 += x2.x*w0[7]; a8 += x2.x*w0[8];
                    const float* w1 = w0 + 9;
                    a0 += x2.y*w1[0]; a1 += x2.y*w1[1]; a2 += x2.y*w1[2];
                    a3 += x2.y*w1[3]; a4 += x2.y*w1[4]; a5 += x2.y*w1[5];
                    a6 += x2.y*w1[6]; a7 += x2.y*w1[7]; a8 += x2.y*w1[8];
                }
                float x = row[36];
                const float* wp = lw + 36 * 9;
                a0 += x*wp[0]; a1 += x*wp[1]; a2 += x*wp[2];
                a3 += x*wp[3]; a4 += x*wp[4]; a5 += x*wp[5];
                a6 += x*wp[6]; a7 += x*wp[7]; a8 += x*wp[8];
            } else {
                float x = row[37];
                const float* wp = lw + 37 * 9;
                a0 += x*wp[0]; a1 += x*wp[1]; a2 += x*wp[2];
                a3 += x*wp[3]; a4 += x*wp[4]; a5 += x*wp[5];
                a6 += x*wp[6]; a7 += x*wp[7]; a8 += x*wp[8];
                #pragma unroll
                for (int k = 0; k < 18; ++k) {
                    float2 x2 = *(const float2*)(row + 38 + k * 2);
                    const float* w0 = lw + (38 + k * 2) * 9;
                    a0 += x2.x*w0[0]; a1 += x2.x*w0[1]; a2 += x2.x*w0[2];
                    a3 += x2.x*w0[3]; a4 += x2.x*w0[4]; a5 += x2.x*w0[5];
                    a6 += x2.x*w0[6]; a7 += x2.x*w0[7]; a8 += x2.x*w0[8];
                    const float* w1 = w0 + 9;
                    a0 += x2.y*w1[0]; a1 += x2.y*w1[1]; a2 += x2.y*w1[2];
                    a3 += x2.y*w1[3]; a4 += x2.y*w1[4]; a5 += x2.y*w1[5];
                    a6 += x2.y*w1[6]; a7 += x2.y*w1[7]; a8 += x2.y*w1[8];
                }
            }
            a0 += __shfl_xor(a0, 1, 64); a1 += __shfl_xor(a1, 1, 64);
            a2 += __shfl_xor(a2, 1, 64); a3 += __shfl_xor(a3, 1, 64);
            a4 += __shfl_xor(a4, 1, 64); a5 += __shfl_xor(a5, 1, 64);
            a6 += __shfl_xor(a6, 1, 64); a7 += __shfl_xor(a7, 1, 64);
            a8 += __shfl_xor(a8, 1, 64);
            if (!half) {
                ((float4*)sn)[node * 2]     = make_float4(a0, a1, a2, 0.f);
                ((float4*)sn)[node * 2 + 1] = make_float4(a6, a7, a8, 0.f);
                ((float4*)er)[node]         = make_float4(a3, a4, a5, 0.f);
            }
        }
        signalFlag(&flagB[b - B_N0]);
    } else {
        // ---- scan block: 200 dsts = 4 graphs; 8 waves scan E/8 edges each ----
        __shared__ float acc[SRNG * 6];   // 4.8 KB
        __shared__ int wq[8][128];        // 4 KB
        for (int i = tid; i < SRNG * 6; i += 512) acc[i] = 0.f;
        waitFlagsA(flagA, NFLAGA, flagB, NFLAGB);   // includes __syncthreads
        const float4* sn4 = (const float4*)sn;
        const float4* er4 = (const float4*)er;
        const int sb = b - B_S0;
        const int rbase = sb * SRNG;
        int* myq = wq[wave];
        int wcnt = 0, wtail = 0;
        const int SPAN4 = (N_EDGES / 4) / 8;           // 5000
        const int NITER = (SPAN4 + 63) / 64;           // 79 uniform rounds
        const int4* d4 = (const int4*)dst;
        int i0 = wave * SPAN4;
        for (int it = 0; it < NITER; ++it) {
            int j = it * 64 + lane;
            bool valid = j < SPAN4;
            int i = i0 + (valid ? j : 0);
            int4 d = d4[i];
            #pragma unroll
            for (int k = 0; k < 4; ++k) {
                int dd = (k == 0) ? d.x : (k == 1) ? d.y : (k == 2) ? d.z : d.w;
                unsigned rr = (unsigned)(dd - rbase);
                bool match = valid && (rr < SRNG);
                unsigned long long m = __ballot(match);
                if (m) {
                    if (match) {
                        int off = __popcll(m & ((1ULL << lane) - 1ULL));
                        myq[(wcnt + off) & 127] = ((i * 4 + k) << 8) | (int)rr;
                    }
                    wcnt += (int)__popcll(m);
                    if (wcnt - wtail >= 64) {
                        processBatch(myq, wtail, lane, 64, src, sn4, er4, rbase, acc);
                        wtail += 64;
                    }
                }
            }
        }
        int rem = wcnt - wtail;
        if (rem > 0) processBatch(myq, wtail, lane, rem, src, sn4, er4, rbase, acc);
        __syncthreads();
        if (wave < 4) {
            float bg = 0.f;
            for (int i = lane; i < NVB; i += 64) bg += bgvpar[i];
            bg = waveReduceSum(bg);
            float cacc = 0.f;
            if (lane < 50) {
                const float* p = acc + (wave * 50 + lane) * 6;
                if (p[3] > 0.f) cacc = p[0] / p[3] + p[1] / p[4] + p[2] / p[5];
            }
            cacc = waveReduceSum(cacc);
            if (!lane) y[sb * 4 + wave] = cacc * (1.f / 50.f) + bg + c0[0];
        }
    }
}

extern "C" void kernel_launch(void* const* d_in, const int* in_sizes, int n_in,
                              void* d_out, int out_size, void* d_ws, size_t ws_size,
                              hipStream_t stream) {
    const float* feats = (const float*)d_in[0];
    const float* W     = (const float*)d_in[1];
    const float* al    = (const float*)d_in[2];
    const float* ar    = (const float*)d_in[3];
    const float* bias  = (const float*)d_in[4];
    const float* W1    = (const float*)d_in[5];
    const float* b1    = (const float*)d_in[6];
    const float* W2    = (const float*)d_in[7];
    const float* b2    = (const float*)d_in[8];
    const int*   src   = (const int*)d_in[9];
    const int*   dst   = (const int*)d_in[10];
    float* ws = (float*)d_ws;
    float* y  = (float*)d_out;

    hipLaunchKernelGGL(kMega, dim3(NBLK), dim3(512), 0, stream,
                       feats, W, al, ar, bias, W1, b1, W2, b2, src, dst, ws, y);
}

// Round 20
// 68.218 us; speedup vs baseline: 2.5304x; 2.5304x over previous
//
#include <hip/hip_runtime.h>

#define N_NODES 40000
#define N_EDGES 160000
#define N_FEATS 74
#define DD 1024
#define HD 3072
#define N_GRAPHS 800

#define NVB 192               // v-blocks: 16 g's per block
#define NTB 57                // task blocks: 222 L/R dots + c0, 4 waves each
// kScanAll geometry
#define SNR 200               // blocks = dst ranges
#define SRNG 200              // dsts per range (= 4 graphs)
#define SNTHR 1024            // 16 waves per block

__device__ __forceinline__ float waveReduceSum(float v) {
    #pragma unroll
    for (int off = 32; off > 0; off >>= 1)
        v += __shfl_down(v, off, 64);
    return v;
}
__device__ __forceinline__ float lrelu02(float x) { return x > 0.f ? x : 0.2f * x; }

// ---- K1 kVFused: identical to R18 (proven) ----
__global__ __launch_bounds__(256) void kVFused(
    const float* __restrict__ W1, const float* __restrict__ W2,
    const float* __restrict__ b1, const float* __restrict__ b2,
    const float* __restrict__ W, const float* __restrict__ al,
    const float* __restrict__ ar, const float* __restrict__ bias,
    float* __restrict__ c0, float* __restrict__ bgvpar,
    float* __restrict__ wvpar, float* __restrict__ lw6) {
    int wave = threadIdx.x >> 6, lane = threadIdx.x & 63;
    if (blockIdx.x < NVB) {
        __shared__ float vs[16];
        int b = blockIdx.x;
        int g0 = b * 16;
        const float4* w2v = (const float4*)W2;
        #pragma unroll
        for (int q = 0; q < 4; ++q) {
            int g = g0 + wave * 4 + q;
            const float4* row = (const float4*)(W1 + (size_t)g * DD);
            float acc = 0.f;
            #pragma unroll
            for (int k = 0; k < 4; ++k) {
                float4 a = row[lane + 64 * k];
                float4 bb = w2v[lane + 64 * k];
                acc += a.x * bb.x + a.y * bb.y + a.z * bb.z + a.w * bb.w;
            }
            acc = waveReduceSum(acc);
            if (!lane) vs[wave * 4 + q] = acc;
        }
        __syncthreads();
        int tid = threadIdx.x;
        if (tid < N_FEATS) {
            const float4* wr = (const float4*)(W + (size_t)tid * HD + g0);
            const float4* vv = (const float4*)vs;
            float s = 0.f;
            #pragma unroll
            for (int k = 0; k < 4; ++k) {
                float4 a = wr[k];
                float4 bb = vv[k];
                s += a.x * bb.x + a.y * bb.y + a.z * bb.z + a.w * bb.w;
            }
            wvpar[b * 80 + tid] = s;
        } else if (tid == N_FEATS) {
            float s = 0.f;
            #pragma unroll
            for (int j = 0; j < 16; ++j) s += vs[j] * bias[g0 + j];
            bgvpar[b] = s;
        }
    } else {
        int t = (blockIdx.x - NVB) * 4 + wave;
        if (t < N_FEATS * 3) {
            int f = t / 3, h = t - f * 3;
            const float4* rw = (const float4*)(W + (size_t)f * HD + h * DD);
            const float4* pl = (const float4*)(al + h * DD);
            const float4* pr = (const float4*)(ar + h * DD);
            float aL = 0.f, aR = 0.f;
            #pragma unroll
            for (int k = 0; k < 4; ++k) {
                float4 x = rw[lane + 64 * k];
                float4 l4 = pl[lane + 64 * k];
                float4 r4 = pr[lane + 64 * k];
                aL += x.x * l4.x + x.y * l4.y + x.z * l4.z + x.w * l4.w;
                aR += x.x * r4.x + x.y * r4.y + x.z * r4.z + x.w * r4.w;
            }
            aL = waveReduceSum(aL); aR = waveReduceSum(aR);
            if (!lane) { lw6[f * 6 + h] = aL; lw6[f * 6 + 3 + h] = aR; }
        } else if (t == N_FEATS * 3) {
            const float4* pb1 = (const float4*)b1;
            const float4* w2v = (const float4*)W2;
            float acc = 0.f;
            #pragma unroll
            for (int k = 0; k < 4; ++k) {
                float4 a = pb1[lane + 64 * k];
                float4 bb = w2v[lane + 64 * k];
                acc += a.x * bb.x + a.y * bb.y + a.z * bb.z + a.w * bb.w;
            }
            acc = waveReduceSum(acc);
            if (!lane) c0[0] = acc + b2[0];
        }
    }
}

// process a dense batch from the wave's queue: on-demand src projection
__device__ __forceinline__ void processBatch(const int* myq, int wtail, int lane, int nact,
        const int* __restrict__ src, const float* __restrict__ feats,
        const float* lw, const float* erL, float* acc) {
    if (lane < nact) {
        int pk = myq[(wtail + lane) & 127];
        int rr = pk & 255;
        int e  = ((unsigned)pk) >> 8;
        int s  = src[e];
        const float2* fr2 = (const float2*)(feats + (size_t)s * N_FEATS);
        float el0=0,el1=0,el2=0,hv0=0,hv1=0,hv2=0;
        #pragma unroll 4
        for (int k = 0; k < 37; ++k) {
            float2 x2 = fr2[k];
            const float* wA = lw + (k * 2) * 9;
            el0 += x2.x*wA[0]; el1 += x2.x*wA[1]; el2 += x2.x*wA[2];
            hv0 += x2.x*wA[6]; hv1 += x2.x*wA[7]; hv2 += x2.x*wA[8];
            const float* wB = wA + 9;
            el0 += x2.y*wB[0]; el1 += x2.y*wB[1]; el2 += x2.y*wB[2];
            hv0 += x2.y*wB[6]; hv1 += x2.y*wB[7]; hv2 += x2.y*wB[8];
        }
        const float* er = erL + rr * 4;
        float e0 = expf(lrelu02(el0 + er[0]));
        float e1 = expf(lrelu02(el1 + er[1]));
        float e2 = expf(lrelu02(el2 + er[2]));
        float* p = acc + rr * 6;
        atomicAdd(p + 0, e0 * hv0);
        atomicAdd(p + 1, e1 * hv1);
        atomicAdd(p + 2, e2 * hv2);
        atomicAdd(p + 3, e0);
        atomicAdd(p + 4, e1);
        atomicAdd(p + 5, e2);
    }
}

// ---- K2 kScanAll: lw build + local er + barrier-free scan + pooling ----
__global__ __launch_bounds__(SNTHR) void kScanAll(const float* __restrict__ feats,
        const int* __restrict__ src, const int* __restrict__ dst,
        const float* __restrict__ lw6, const float* __restrict__ wvpar,
        const float* __restrict__ bgvpar, const float* __restrict__ c0,
        float* __restrict__ y) {
    __shared__ float lw[N_FEATS * 9];   // 2.7 KB
    __shared__ float erL[SRNG * 4];     // 3.2 KB
    __shared__ float acc[SRNG * 6];     // 4.8 KB
    __shared__ int wq[16][128];         // 8 KB
    int tid = threadIdx.x, wave = tid >> 6, lane = tid & 63;
    const int rbase = blockIdx.x * SRNG;
    // phase 1: zero acc, build lw (L/R from lw6, V summed from wvpar)
    for (int i = tid; i < SRNG * 6; i += SNTHR) acc[i] = 0.f;
    if (tid < N_FEATS * 6)
        lw[(tid / 6) * 9 + (tid % 6)] = lw6[tid];
    else if (tid < N_FEATS * 6 + N_FEATS * 3) {
        int j = tid - N_FEATS * 6;       // j = f*3+h
        int f = j / 3, h = j - f * 3;
        float s = 0.f;
        #pragma unroll 8
        for (int bb = 0; bb < 64; ++bb)
            s += wvpar[(h * 64 + bb) * 80 + f];
        lw[f * 9 + 6 + h] = s;
    }
    __syncthreads();
    // phase 2: er for own 200 dsts
    if (tid < SRNG * 3) {
        int nloc = tid / 3, h = tid - nloc * 3;
        const float2* fr2 = (const float2*)(feats + (size_t)(rbase + nloc) * N_FEATS);
        float s = 0.f;
        #pragma unroll 4
        for (int k = 0; k < 37; ++k) {
            float2 x2 = fr2[k];
            s += x2.x * lw[(k * 2) * 9 + 3 + h] + x2.y * lw[(k * 2 + 1) * 9 + 3 + h];
        }
        erL[nloc * 4 + h] = s;
    }
    __syncthreads();
    // phase 3: barrier-free ballot-compacted scan (uniform trip count)
    int* myq = wq[wave];
    int wcnt = 0, wtail = 0;
    const int SPAN4 = (N_EDGES / 4) / 16;          // 2500
    const int NITER = (SPAN4 + 63) / 64;           // 40 rounds
    const int4* d4 = (const int4*)dst;
    int i0 = wave * SPAN4;
    for (int it = 0; it < NITER; ++it) {
        int j = it * 64 + lane;
        bool valid = j < SPAN4;
        int i = i0 + (valid ? j : 0);
        int4 d = d4[i];
        #pragma unroll
        for (int k = 0; k < 4; ++k) {
            int dd = (k == 0) ? d.x : (k == 1) ? d.y : (k == 2) ? d.z : d.w;
            unsigned rr = (unsigned)(dd - rbase);
            bool match = valid && (rr < SRNG);
            unsigned long long m = __ballot(match);
            if (m) {
                if (match) {
                    int off = __popcll(m & ((1ULL << lane) - 1ULL));
                    myq[(wcnt + off) & 127] = ((i * 4 + k) << 8) | (int)rr;
                }
                wcnt += (int)__popcll(m);
                if (wcnt - wtail >= 64) {
                    processBatch(myq, wtail, lane, 64, src, feats, lw, erL, acc);
                    wtail += 64;
                }
            }
        }
    }
    int rem = wcnt - wtail;
    if (rem > 0) processBatch(myq, wtail, lane, rem, src, feats, lw, erL, acc);
    __syncthreads();
    // phase 4: pooling, waves 0..3 -> graphs blockIdx*4 + wave
    if (wave < 4) {
        float b = 0.f;
        for (int i = lane; i < NVB; i += 64) b += bgvpar[i];
        b = waveReduceSum(b);
        float cacc = 0.f;
        if (lane < 50) {
            const float* p = acc + (wave * 50 + lane) * 6;
            if (p[3] > 0.f) cacc = p[0] / p[3] + p[1] / p[4] + p[2] / p[5];
        }
        cacc = waveReduceSum(cacc);
        if (!lane) y[blockIdx.x * 4 + wave] = cacc * (1.f / 50.f) + b + c0[0];
    }
}

extern "C" void kernel_launch(void* const* d_in, const int* in_sizes, int n_in,
                              void* d_out, int out_size, void* d_ws, size_t ws_size,
                              hipStream_t stream) {
    const float* feats = (const float*)d_in[0];
    const float* W     = (const float*)d_in[1];
    const float* al    = (const float*)d_in[2];
    const float* ar    = (const float*)d_in[3];
    const float* bias  = (const float*)d_in[4];
    const float* W1    = (const float*)d_in[5];
    const float* b1    = (const float*)d_in[6];
    const float* W2    = (const float*)d_in[7];
    const float* b2    = (const float*)d_in[8];
    const int*   src   = (const int*)d_in[9];
    const int*   dst   = (const int*)d_in[10];

    float* ws     = (float*)d_ws;
    float* lw6    = ws;                    // 444 (pad 448)
    float* c0     = ws + 448;              // 1
    float* bgvpar = ws + 512;              // 192
    float* wvpar  = ws + 1024;             // 192*80 = 15360
    float* y      = (float*)d_out;

    hipLaunchKernelGGL(kVFused, dim3(NVB + NTB), dim3(256), 0, stream,
                       W1, W2, b1, b2, W, al, ar, bias, c0, bgvpar, wvpar, lw6);
    hipLaunchKernelGGL(kScanAll, dim3(SNR), dim3(SNTHR), 0, stream,
                       feats, src, dst, lw6, wvpar, bgvpar, c0, y);
}

// Round 21
// 55.641 us; speedup vs baseline: 3.1023x; 1.2260x over previous
//
#include <hip/hip_runtime.h>

#define N_NODES 40000
#define N_EDGES 160000
#define N_FEATS 74
#define DD 1024
#define HD 3072
#define N_GRAPHS 800

#define NVB 192               // v-blocks: 16 g's per block
#define NTB 57                // task blocks: 222 L/R dots + c0, 4 waves each
// kScanAll geometry
#define SNR 200               // blocks = dst ranges
#define SRNG 200              // dsts per range (= 4 graphs)
#define SNTHR 1024            // 16 waves per block

__device__ __forceinline__ float waveReduceSum(float v) {
    #pragma unroll
    for (int off = 32; off > 0; off >>= 1)
        v += __shfl_down(v, off, 64);
    return v;
}
__device__ __forceinline__ float lrelu02(float x) { return x > 0.f ? x : 0.2f * x; }

// ---- K1 kVFused: identical to R18 (proven) ----
__global__ __launch_bounds__(256) void kVFused(
    const float* __restrict__ W1, const float* __restrict__ W2,
    const float* __restrict__ b1, const float* __restrict__ b2,
    const float* __restrict__ W, const float* __restrict__ al,
    const float* __restrict__ ar, const float* __restrict__ bias,
    float* __restrict__ c0, float* __restrict__ bgvpar,
    float* __restrict__ wvpar, float* __restrict__ lw6) {
    int wave = threadIdx.x >> 6, lane = threadIdx.x & 63;
    if (blockIdx.x < NVB) {
        __shared__ float vs[16];
        int b = blockIdx.x;
        int g0 = b * 16;
        const float4* w2v = (const float4*)W2;
        #pragma unroll
        for (int q = 0; q < 4; ++q) {
            int g = g0 + wave * 4 + q;
            const float4* row = (const float4*)(W1 + (size_t)g * DD);
            float acc = 0.f;
            #pragma unroll
            for (int k = 0; k < 4; ++k) {
                float4 a = row[lane + 64 * k];
                float4 bb = w2v[lane + 64 * k];
                acc += a.x * bb.x + a.y * bb.y + a.z * bb.z + a.w * bb.w;
            }
            acc = waveReduceSum(acc);
            if (!lane) vs[wave * 4 + q] = acc;
        }
        __syncthreads();
        int tid = threadIdx.x;
        if (tid < N_FEATS) {
            const float4* wr = (const float4*)(W + (size_t)tid * HD + g0);
            const float4* vv = (const float4*)vs;
            float s = 0.f;
            #pragma unroll
            for (int k = 0; k < 4; ++k) {
                float4 a = wr[k];
                float4 bb = vv[k];
                s += a.x * bb.x + a.y * bb.y + a.z * bb.z + a.w * bb.w;
            }
            wvpar[b * 80 + tid] = s;
        } else if (tid == N_FEATS) {
            float s = 0.f;
            #pragma unroll
            for (int j = 0; j < 16; ++j) s += vs[j] * bias[g0 + j];
            bgvpar[b] = s;
        }
    } else {
        int t = (blockIdx.x - NVB) * 4 + wave;
        if (t < N_FEATS * 3) {
            int f = t / 3, h = t - f * 3;
            const float4* rw = (const float4*)(W + (size_t)f * HD + h * DD);
            const float4* pl = (const float4*)(al + h * DD);
            const float4* pr = (const float4*)(ar + h * DD);
            float aL = 0.f, aR = 0.f;
            #pragma unroll
            for (int k = 0; k < 4; ++k) {
                float4 x = rw[lane + 64 * k];
                float4 l4 = pl[lane + 64 * k];
                float4 r4 = pr[lane + 64 * k];
                aL += x.x * l4.x + x.y * l4.y + x.z * l4.z + x.w * l4.w;
                aR += x.x * r4.x + x.y * r4.y + x.z * r4.z + x.w * r4.w;
            }
            aL = waveReduceSum(aL); aR = waveReduceSum(aR);
            if (!lane) { lw6[f * 6 + h] = aL; lw6[f * 6 + 3 + h] = aR; }
        } else if (t == N_FEATS * 3) {
            const float4* pb1 = (const float4*)b1;
            const float4* w2v = (const float4*)W2;
            float acc = 0.f;
            #pragma unroll
            for (int k = 0; k < 4; ++k) {
                float4 a = pb1[lane + 64 * k];
                float4 bb = w2v[lane + 64 * k];
                acc += a.x * bb.x + a.y * bb.y + a.z * bb.z + a.w * bb.w;
            }
            acc = waveReduceSum(acc);
            if (!lane) c0[0] = acc + b2[0];
        }
    }
}

// process up to 8 queued edges: 8 lanes per edge, coalesced row chunks,
// 3-level shfl_xor group reduce, sub-lane 0 finalizes.
__device__ __forceinline__ void processBatch8(const int* myq, int wtail, int lane, int nact,
        const int* __restrict__ src, const float* __restrict__ feats,
        const float* lw, const float* erL, float* acc) {
    int grp = lane >> 3, sl = lane & 7;
    bool active = grp < nact;
    int pk = myq[(wtail + grp) & 127];
    int rr = pk & 255;
    int e  = ((unsigned)pk) >> 8;
    int s  = active ? src[e] : 0;
    const float2* fr2 = (const float2*)(feats + (size_t)s * N_FEATS);
    float el0=0,el1=0,el2=0,hv0=0,hv1=0,hv2=0;
    #pragma unroll
    for (int k = 0; k < 5; ++k) {
        int j = sl + 8 * k;
        if (j < 37) {
            float2 x2 = fr2[j];
            const float* wA = lw + (2 * j) * 9;
            el0 += x2.x*wA[0]; el1 += x2.x*wA[1]; el2 += x2.x*wA[2];
            hv0 += x2.x*wA[6]; hv1 += x2.x*wA[7]; hv2 += x2.x*wA[8];
            const float* wB = wA + 9;
            el0 += x2.y*wB[0]; el1 += x2.y*wB[1]; el2 += x2.y*wB[2];
            hv0 += x2.y*wB[6]; hv1 += x2.y*wB[7]; hv2 += x2.y*wB[8];
        }
    }
    #pragma unroll
    for (int m = 1; m < 8; m <<= 1) {
        el0 += __shfl_xor(el0, m, 64); el1 += __shfl_xor(el1, m, 64);
        el2 += __shfl_xor(el2, m, 64);
        hv0 += __shfl_xor(hv0, m, 64); hv1 += __shfl_xor(hv1, m, 64);
        hv2 += __shfl_xor(hv2, m, 64);
    }
    if (active && sl == 0) {
        const float* er = erL + rr * 4;
        float e0 = expf(lrelu02(el0 + er[0]));
        float e1 = expf(lrelu02(el1 + er[1]));
        float e2 = expf(lrelu02(el2 + er[2]));
        float* p = acc + rr * 6;
        atomicAdd(p + 0, e0 * hv0);
        atomicAdd(p + 1, e1 * hv1);
        atomicAdd(p + 2, e2 * hv2);
        atomicAdd(p + 3, e0);
        atomicAdd(p + 4, e1);
        atomicAdd(p + 5, e2);
    }
}

// ---- K2 kScanAll: lw build + local er + barrier-free scan + pooling ----
__global__ __launch_bounds__(SNTHR) void kScanAll(const float* __restrict__ feats,
        const int* __restrict__ src, const int* __restrict__ dst,
        const float* __restrict__ lw6, const float* __restrict__ wvpar,
        const float* __restrict__ bgvpar, const float* __restrict__ c0,
        float* __restrict__ y) {
    __shared__ float lw[N_FEATS * 9];   // 2.7 KB
    __shared__ float erL[SRNG * 4];     // 3.2 KB
    __shared__ float acc[SRNG * 6];     // 4.8 KB
    __shared__ int wq[16][128];         // 8 KB
    int tid = threadIdx.x, wave = tid >> 6, lane = tid & 63;
    const int rbase = blockIdx.x * SRNG;
    // phase 1: zero acc, build lw (L/R from lw6, V summed from wvpar)
    for (int i = tid; i < SRNG * 6; i += SNTHR) acc[i] = 0.f;
    if (tid < N_FEATS * 6)
        lw[(tid / 6) * 9 + (tid % 6)] = lw6[tid];
    else if (tid < N_FEATS * 6 + N_FEATS * 3) {
        int j = tid - N_FEATS * 6;       // j = f*3+h
        int f = j / 3, h = j - f * 3;
        float s = 0.f;
        #pragma unroll 8
        for (int bb = 0; bb < 64; ++bb)
            s += wvpar[(h * 64 + bb) * 80 + f];
        lw[f * 9 + 6 + h] = s;
    }
    __syncthreads();
    // phase 2: er for own 200 dsts
    if (tid < SRNG * 3) {
        int nloc = tid / 3, h = tid - nloc * 3;
        const float2* fr2 = (const float2*)(feats + (size_t)(rbase + nloc) * N_FEATS);
        float s = 0.f;
        #pragma unroll 4
        for (int k = 0; k < 37; ++k) {
            float2 x2 = fr2[k];
            s += x2.x * lw[(k * 2) * 9 + 3 + h] + x2.y * lw[(k * 2 + 1) * 9 + 3 + h];
        }
        erL[nloc * 4 + h] = s;
    }
    __syncthreads();
    // phase 3: barrier-free ballot-compacted scan (uniform trip count),
    // draining in 8-edge coalesced batches
    int* myq = wq[wave];
    int wcnt = 0, wtail = 0;
    const int SPAN4 = (N_EDGES / 4) / 16;          // 2500
    const int NITER = (SPAN4 + 63) / 64;           // 40 rounds
    const int4* d4 = (const int4*)dst;
    int i0 = wave * SPAN4;
    for (int it = 0; it < NITER; ++it) {
        int j = it * 64 + lane;
        bool valid = j < SPAN4;
        int i = i0 + (valid ? j : 0);
        int4 d = d4[i];
        #pragma unroll
        for (int k = 0; k < 4; ++k) {
            int dd = (k == 0) ? d.x : (k == 1) ? d.y : (k == 2) ? d.z : d.w;
            unsigned rr = (unsigned)(dd - rbase);
            bool match = valid && (rr < SRNG);
            unsigned long long m = __ballot(match);
            if (m) {
                if (match) {
                    int off = __popcll(m & ((1ULL << lane) - 1ULL));
                    myq[(wcnt + off) & 127] = ((i * 4 + k) << 8) | (int)rr;
                }
                wcnt += (int)__popcll(m);
                while (wcnt - wtail >= 8) {
                    processBatch8(myq, wtail, lane, 8, src, feats, lw, erL, acc);
                    wtail += 8;
                }
            }
        }
    }
    int rem = wcnt - wtail;
    if (rem > 0) processBatch8(myq, wtail, lane, rem, src, feats, lw, erL, acc);
    __syncthreads();
    // phase 4: pooling, waves 0..3 -> graphs blockIdx*4 + wave
    if (wave < 4) {
        float b = 0.f;
        for (int i = lane; i < NVB; i += 64) b += bgvpar[i];
        b = waveReduceSum(b);
        float cacc = 0.f;
        if (lane < 50) {
            const float* p = acc + (wave * 50 + lane) * 6;
            if (p[3] > 0.f) cacc = p[0] / p[3] + p[1] / p[4] + p[2] / p[5];
        }
        cacc = waveReduceSum(cacc);
        if (!lane) y[blockIdx.x * 4 + wave] = cacc * (1.f / 50.f) + b + c0[0];
    }
}

extern "C" void kernel_launch(void* const* d_in, const int* in_sizes, int n_in,
                              void* d_out, int out_size, void* d_ws, size_t ws_size,
                              hipStream_t stream) {
    const float* feats = (const float*)d_in[0];
    const float* W     = (const float*)d_in[1];
    const float* al    = (const float*)d_in[2];
    const float* ar    = (const float*)d_in[3];
    const float* bias  = (const float*)d_in[4];
    const float* W1    = (const float*)d_in[5];
    const float* b1    = (const float*)d_in[6];
    const float* W2    = (const float*)d_in[7];
    const float* b2    = (const float*)d_in[8];
    const int*   src   = (const int*)d_in[9];
    const int*   dst   = (const int*)d_in[10];

    float* ws     = (float*)d_ws;
    float* lw6    = ws;                    // 444 (pad 448)
    float* c0     = ws + 448;              // 1
    float* bgvpar = ws + 512;              // 192
    float* wvpar  = ws + 1024;             // 192*80 = 15360
    float* y      = (float*)d_out;

    hipLaunchKernelGGL(kVFused, dim3(NVB + NTB), dim3(256), 0, stream,
                       W1, W2, b1, b2, W, al, ar, bias, c0, bgvpar, wvpar, lw6);
    hipLaunchKernelGGL(kScanAll, dim3(SNR), dim3(SNTHR), 0, stream,
                       feats, src, dst, lw6, wvpar, bgvpar, c0, y);
}

// Round 22
// 50.953 us; speedup vs baseline: 3.3877x; 1.0920x over previous
//
#include <hip/hip_runtime.h>

#define N_NODES 40000
#define N_EDGES 160000
#define N_FEATS 74
#define DD 1024
#define HD 3072
#define N_GRAPHS 800

#define NVB 192               // v-blocks: 16 g's per block (64 per head)
#define NTB 57                // task blocks: 222 L/R dots + c0, 4 waves each
// kScanAll geometry
#define SNR 200               // blocks = dst ranges
#define SRNG 200              // dsts per range (= 4 graphs)
#define SNTHR 1024            // 16 waves per block

__device__ __forceinline__ float waveReduceSum(float v) {
    #pragma unroll
    for (int off = 32; off > 0; off >>= 1)
        v += __shfl_down(v, off, 64);
    return v;
}
__device__ __forceinline__ float lrelu02(float x) { return x > 0.f ? x : 0.2f * x; }

// ---- K1 kVFused: R18-proven, wvpar stored TRANSPOSED for coalesced reduce ----
__global__ __launch_bounds__(256) void kVFused(
    const float* __restrict__ W1, const float* __restrict__ W2,
    const float* __restrict__ b1, const float* __restrict__ b2,
    const float* __restrict__ W, const float* __restrict__ al,
    const float* __restrict__ ar, const float* __restrict__ bias,
    float* __restrict__ c0, float* __restrict__ bgvpar,
    float* __restrict__ wvpar, float* __restrict__ lw6) {
    int wave = threadIdx.x >> 6, lane = threadIdx.x & 63;
    if (blockIdx.x < NVB) {
        __shared__ float vs[16];
        int b = blockIdx.x;
        int g0 = b * 16;
        int h = b >> 6;                      // 64 v-blocks per head
        const float4* w2v = (const float4*)W2;
        #pragma unroll
        for (int q = 0; q < 4; ++q) {
            int g = g0 + wave * 4 + q;
            const float4* row = (const float4*)(W1 + (size_t)g * DD);
            float acc = 0.f;
            #pragma unroll
            for (int k = 0; k < 4; ++k) {
                float4 a = row[lane + 64 * k];
                float4 bb = w2v[lane + 64 * k];
                acc += a.x * bb.x + a.y * bb.y + a.z * bb.z + a.w * bb.w;
            }
            acc = waveReduceSum(acc);
            if (!lane) vs[wave * 4 + q] = acc;
        }
        __syncthreads();
        int tid = threadIdx.x;
        if (tid < N_FEATS) {
            const float4* wr = (const float4*)(W + (size_t)tid * HD + g0);
            const float4* vv = (const float4*)vs;
            float s = 0.f;
            #pragma unroll
            for (int k = 0; k < 4; ++k) {
                float4 a = wr[k];
                float4 bb = vv[k];
                s += a.x * bb.x + a.y * bb.y + a.z * bb.z + a.w * bb.w;
            }
            wvpar[((size_t)(h * N_FEATS + tid)) * 64 + (b & 63)] = s;  // transposed
        } else if (tid == N_FEATS) {
            float s = 0.f;
            #pragma unroll
            for (int j = 0; j < 16; ++j) s += vs[j] * bias[g0 + j];
            bgvpar[b] = s;
        }
    } else {
        int t = (blockIdx.x - NVB) * 4 + wave;
        if (t < N_FEATS * 3) {
            int f = t / 3, h = t - f * 3;
            const float4* rw = (const float4*)(W + (size_t)f * HD + h * DD);
            const float4* pl = (const float4*)(al + h * DD);
            const float4* pr = (const float4*)(ar + h * DD);
            float aL = 0.f, aR = 0.f;
            #pragma unroll
            for (int k = 0; k < 4; ++k) {
                float4 x = rw[lane + 64 * k];
                float4 l4 = pl[lane + 64 * k];
                float4 r4 = pr[lane + 64 * k];
                aL += x.x * l4.x + x.y * l4.y + x.z * l4.z + x.w * l4.w;
                aR += x.x * r4.x + x.y * r4.y + x.z * r4.z + x.w * r4.w;
            }
            aL = waveReduceSum(aL); aR = waveReduceSum(aR);
            if (!lane) { lw6[f * 6 + h] = aL; lw6[f * 6 + 3 + h] = aR; }
        } else if (t == N_FEATS * 3) {
            const float4* pb1 = (const float4*)b1;
            const float4* w2v = (const float4*)W2;
            float acc = 0.f;
            #pragma unroll
            for (int k = 0; k < 4; ++k) {
                float4 a = pb1[lane + 64 * k];
                float4 bb = w2v[lane + 64 * k];
                acc += a.x * bb.x + a.y * bb.y + a.z * bb.z + a.w * bb.w;
            }
            acc = waveReduceSum(acc);
            if (!lane) c0[0] = acc + b2[0];
        }
    }
}

// process up to 8 queued edges: 8 lanes per edge (proven R21)
__device__ __forceinline__ void processBatch8(const int* myq, int wtail, int lane, int nact,
        const int* __restrict__ src, const float* __restrict__ feats,
        const float* lw, const float* erL, float* acc) {
    int grp = lane >> 3, sl = lane & 7;
    bool active = grp < nact;
    int pk = myq[(wtail + grp) & 127];
    int rr = pk & 255;
    int e  = ((unsigned)pk) >> 8;
    int s  = active ? src[e] : 0;
    const float2* fr2 = (const float2*)(feats + (size_t)s * N_FEATS);
    float el0=0,el1=0,el2=0,hv0=0,hv1=0,hv2=0;
    #pragma unroll
    for (int k = 0; k < 5; ++k) {
        int j = sl + 8 * k;
        if (j < 37) {
            float2 x2 = fr2[j];
            const float* wA = lw + (2 * j) * 9;
            el0 += x2.x*wA[0]; el1 += x2.x*wA[1]; el2 += x2.x*wA[2];
            hv0 += x2.x*wA[6]; hv1 += x2.x*wA[7]; hv2 += x2.x*wA[8];
            const float* wB = wA + 9;
            el0 += x2.y*wB[0]; el1 += x2.y*wB[1]; el2 += x2.y*wB[2];
            hv0 += x2.y*wB[6]; hv1 += x2.y*wB[7]; hv2 += x2.y*wB[8];
        }
    }
    #pragma unroll
    for (int m = 1; m < 8; m <<= 1) {
        el0 += __shfl_xor(el0, m, 64); el1 += __shfl_xor(el1, m, 64);
        el2 += __shfl_xor(el2, m, 64);
        hv0 += __shfl_xor(hv0, m, 64); hv1 += __shfl_xor(hv1, m, 64);
        hv2 += __shfl_xor(hv2, m, 64);
    }
    if (active && sl == 0) {
        const float* er = erL + rr * 4;
        float e0 = expf(lrelu02(el0 + er[0]));
        float e1 = expf(lrelu02(el1 + er[1]));
        float e2 = expf(lrelu02(el2 + er[2]));
        float* p = acc + rr * 6;
        atomicAdd(p + 0, e0 * hv0);
        atomicAdd(p + 1, e1 * hv1);
        atomicAdd(p + 2, e2 * hv2);
        atomicAdd(p + 3, e0);
        atomicAdd(p + 4, e1);
        atomicAdd(p + 5, e2);
    }
}

// ---- K2 kScanAll: coalesced table/er builds + barrier-free scan + pooling ----
__global__ __launch_bounds__(SNTHR) void kScanAll(const float* __restrict__ feats,
        const int* __restrict__ src, const int* __restrict__ dst,
        const float* __restrict__ lw6, const float* __restrict__ wvpar,
        const float* __restrict__ bgvpar, const float* __restrict__ c0,
        float* __restrict__ y) {
    __shared__ float lw[N_FEATS * 9];   // 2.7 KB
    __shared__ float erL[SRNG * 4];     // 3.2 KB
    __shared__ float acc[SRNG * 6];     // 4.8 KB
    __shared__ int wq[16][128];         // 8 KB
    int tid = threadIdx.x, wave = tid >> 6, lane = tid & 63;
    const int rbase = blockIdx.x * SRNG;
    // phase 1: zero acc; V-table via 4-lane coalesced groups; L/R direct
    for (int i = tid; i < SRNG * 6; i += SNTHR) acc[i] = 0.f;
    if (tid < 222 * 4) {
        int g4 = tid >> 2, sl = tid & 3;     // g4 = h*74+f
        int h = g4 / N_FEATS, f = g4 - h * N_FEATS;
        const float* p = wvpar + (size_t)g4 * 64 + sl * 16;
        float s = 0.f;
        #pragma unroll
        for (int k = 0; k < 16; ++k) s += p[k];
        s += __shfl_xor(s, 1, 64);
        s += __shfl_xor(s, 2, 64);
        if (!sl) lw[f * 9 + 6 + h] = s;
    }
    if (tid < N_FEATS * 6)
        lw[(tid / 6) * 9 + (tid % 6)] = lw6[tid];
    __syncthreads();
    // phase 2: er for own 200 dsts, 8 lanes per (node,h) task
    for (int base = 0; base < SRNG * 3; base += 128) {
        int task = base + (tid >> 3);
        int sl = tid & 7;
        if (task < SRNG * 3) {
            int nloc = task / 3, h = task - nloc * 3;
            const float2* fr2 = (const float2*)(feats + (size_t)(rbase + nloc) * N_FEATS);
            float s = 0.f;
            #pragma unroll
            for (int k = 0; k < 5; ++k) {
                int j = sl + 8 * k;
                if (j < 37) {
                    float2 x2 = fr2[j];
                    s += x2.x * lw[(2 * j) * 9 + 3 + h] + x2.y * lw[(2 * j + 1) * 9 + 3 + h];
                }
            }
            #pragma unroll
            for (int m = 1; m < 8; m <<= 1) s += __shfl_xor(s, m, 64);
            if (!sl) erL[nloc * 4 + h] = s;
        }
    }
    __syncthreads();
    // phase 3: barrier-free ballot-compacted scan, 8-edge coalesced drains
    int* myq = wq[wave];
    int wcnt = 0, wtail = 0;
    const int SPAN4 = (N_EDGES / 4) / 16;          // 2500
    const int NITER = (SPAN4 + 63) / 64;           // 40 uniform rounds
    const int4* d4 = (const int4*)dst;
    int i0 = wave * SPAN4;
    for (int it = 0; it < NITER; ++it) {
        int j = it * 64 + lane;
        bool valid = j < SPAN4;
        int i = i0 + (valid ? j : 0);
        int4 d = d4[i];
        #pragma unroll
        for (int k = 0; k < 4; ++k) {
            int dd = (k == 0) ? d.x : (k == 1) ? d.y : (k == 2) ? d.z : d.w;
            unsigned rr = (unsigned)(dd - rbase);
            bool match = valid && (rr < SRNG);
            unsigned long long m = __ballot(match);
            if (m) {
                if (match) {
                    int off = __popcll(m & ((1ULL << lane) - 1ULL));
                    myq[(wcnt + off) & 127] = ((i * 4 + k) << 8) | (int)rr;
                }
                wcnt += (int)__popcll(m);
                while (wcnt - wtail >= 8) {
                    processBatch8(myq, wtail, lane, 8, src, feats, lw, erL, acc);
                    wtail += 8;
                }
            }
        }
    }
    int rem = wcnt - wtail;
    if (rem > 0) processBatch8(myq, wtail, lane, rem, src, feats, lw, erL, acc);
    __syncthreads();
    // phase 4: pooling, waves 0..3 -> graphs blockIdx*4 + wave
    if (wave < 4) {
        float b = 0.f;
        for (int i = lane; i < NVB; i += 64) b += bgvpar[i];
        b = waveReduceSum(b);
        float cacc = 0.f;
        if (lane < 50) {
            const float* p = acc + (wave * 50 + lane) * 6;
            if (p[3] > 0.f) cacc = p[0] / p[3] + p[1] / p[4] + p[2] / p[5];
        }
        cacc = waveReduceSum(cacc);
        if (!lane) y[blockIdx.x * 4 + wave] = cacc * (1.f / 50.f) + b + c0[0];
    }
}

extern "C" void kernel_launch(void* const* d_in, const int* in_sizes, int n_in,
                              void* d_out, int out_size, void* d_ws, size_t ws_size,
                              hipStream_t stream) {
    const float* feats = (const float*)d_in[0];
    const float* W     = (const float*)d_in[1];
    const float* al    = (const float*)d_in[2];
    const float* ar    = (const float*)d_in[3];
    const float* bias  = (const float*)d_in[4];
    const float* W1    = (const float*)d_in[5];
    const float* b1    = (const float*)d_in[6];
    const float* W2    = (const float*)d_in[7];
    const float* b2    = (const float*)d_in[8];
    const int*   src   = (const int*)d_in[9];
    const int*   dst   = (const int*)d_in[10];

    float* ws     = (float*)d_ws;
    float* lw6    = ws;                    // 444 (pad 448)
    float* c0     = ws + 448;              // 1
    float* bgvpar = ws + 512;              // 192
    float* wvpar  = ws + 1024;             // 222*64 = 14208
    float* y      = (float*)d_out;

    hipLaunchKernelGGL(kVFused, dim3(NVB + NTB), dim3(256), 0, stream,
                       W1, W2, b1, b2, W, al, ar, bias, c0, bgvpar, wvpar, lw6);
    hipLaunchKernelGGL(kScanAll, dim3(SNR), dim3(SNTHR), 0, stream,
                       feats, src, dst, lw6, wvpar, bgvpar, c0, y);
}